// Round 14
// baseline (104.761 us; speedup 1.0000x reference)
//
#include <hip/hip_runtime.h>

// n=4, L=8192, h=8, e=64, fp32 in/out
#define N_      4
#define L_      8192
#define H_      8
#define E_      64
#define NH_     (N_ * H_)
#define STRIDE_ (H_ * E_)          // 512 floats between rows
#define SPLIT_  32                 // s-split for phase 1 (1024 blocks)
#define RPB_    (L_ / SPLIT_)      // 256 rows per block
#define CHR_    64                 // rows per staged chunk
#define NCHK_   (RPB_ / CHR_)      // 4 chunks

typedef short bf16x8 __attribute__((ext_vector_type(8)));
typedef float f32x16 __attribute__((ext_vector_type(16)));

__device__ __forceinline__ float featmap(float x) {
    float xs = x * 0.35355339059327373f;   // * 64^-0.25
    return xs > 0.0f ? xs + 1.0f : __expf(xs);
}
__device__ __forceinline__ unsigned short f2bf(float f) {   // RNE f32->bf16
    union { float f; unsigned u; } c{f};
    unsigned r = c.u + 0x7FFFu + ((c.u >> 16) & 1u);
    return (unsigned short)(r >> 16);
}
__device__ __forceinline__ unsigned cvt_pk_bf16(float lo, float hi) {
    unsigned r;
    asm("v_cvt_pk_bf16_f32 %0, %1, %2" : "=v"(r) : "v"(lo), "v"(hi));
    return r;
}
__device__ __forceinline__ int swz_slot(int d, int sp4) {   // sp4 = sp>>2
    return (sp4 ^ (d & 7) ^ ((d >> 2) & 7)) & 7;
}

// ---------------------------------------------------------------------------
// Phase 1 (r12 verbatim, passing at absmax 2.44e-4).
// ---------------------------------------------------------------------------
__global__ __launch_bounds__(256) void la_kv(
    const float* __restrict__ keys, const float* __restrict__ values,
    float* __restrict__ pkv, float* __restrict__ pks)
{
    const int blk = blockIdx.x;
    const int nh = blk / SPLIT_, chunk = blk % SPLIT_;
    const int n = nh / H_, h = nh % H_;
    const int t = threadIdx.x, l = t & 63;
    const int w = t >> 6, wd = w >> 1, wm = w & 1;
    const int lm = l & 31, lh = l >> 5;
    const int pr = t >> 3, c = t & 7;      // row-pair 0..31, col-octet 0..7

    __shared__ unsigned Kb[2][CHR_][32];   // [buf][d][swizzled s-pair] 16 KB
    __shared__ unsigned Vb[2][CHR_][32];   // 16 KB

    f32x16 acc = {0,0,0,0,0,0,0,0,0,0,0,0,0,0,0,0};
    float ksp[8] = {0.f,0.f,0.f,0.f,0.f,0.f,0.f,0.f};

    const size_t base = (size_t)n * (L_ * H_ * E_) + (size_t)h * E_;
    const size_t rbase = base + (size_t)(chunk * RPB_ + 2 * pr) * STRIDE_ + 4 * c;

    float4 kr0 = *(const float4*)(keys + rbase);
    float4 kr1 = *(const float4*)(keys + rbase + 32);
    float4 kr2 = *(const float4*)(keys + rbase + STRIDE_);
    float4 kr3 = *(const float4*)(keys + rbase + STRIDE_ + 32);
    float4 vr0 = *(const float4*)(values + rbase);
    float4 vr1 = *(const float4*)(values + rbase + 32);
    float4 vr2 = *(const float4*)(values + rbase + STRIDE_);
    float4 vr3 = *(const float4*)(values + rbase + STRIDE_ + 32);

    #pragma unroll
    for (int ch = 0; ch < NCHK_; ++ch) {
        const int buf = ch & 1;
        float a0[4] = {kr0.x, kr0.y, kr0.z, kr0.w};
        float a1[4] = {kr1.x, kr1.y, kr1.z, kr1.w};
        float a2[4] = {kr2.x, kr2.y, kr2.z, kr2.w};
        float a3[4] = {kr3.x, kr3.y, kr3.z, kr3.w};
        float b0[4] = {vr0.x, vr0.y, vr0.z, vr0.w};
        float b1[4] = {vr1.x, vr1.y, vr1.z, vr1.w};
        float b2[4] = {vr2.x, vr2.y, vr2.z, vr2.w};
        float b3[4] = {vr3.x, vr3.y, vr3.z, vr3.w};

        #pragma unroll
        for (int i = 0; i < 4; ++i) {
            const float f0 = featmap(a0[i]), f1 = featmap(a1[i]);
            const float f2 = featmap(a2[i]), f3 = featmap(a3[i]);
            ksp[i]     += f0 + f2;
            ksp[4 + i] += f1 + f3;
            const int dl = 4 * c + i, dh = 32 + 4 * c + i;
            const int wl = swz_slot(dl, pr >> 2) * 4 + (pr & 3);
            const int wh = swz_slot(dh, pr >> 2) * 4 + (pr & 3);
            Kb[buf][dl][wl] = cvt_pk_bf16(f0, f2);      // lo = even s
            Kb[buf][dh][wh] = cvt_pk_bf16(f1, f3);
            Vb[buf][dl][wl] = cvt_pk_bf16(b0[i], b2[i]);
            Vb[buf][dh][wh] = cvt_pk_bf16(b1[i], b3[i]);
        }

        __syncthreads();

        if (ch + 1 < NCHK_) {
            const size_t nb = rbase + (size_t)(ch + 1) * CHR_ * STRIDE_;
            kr0 = *(const float4*)(keys + nb);
            kr1 = *(const float4*)(keys + nb + 32);
            kr2 = *(const float4*)(keys + nb + STRIDE_);
            kr3 = *(const float4*)(keys + nb + STRIDE_ + 32);
            vr0 = *(const float4*)(values + nb);
            vr1 = *(const float4*)(values + nb + 32);
            vr2 = *(const float4*)(values + nb + STRIDE_);
            vr3 = *(const float4*)(values + nb + STRIDE_ + 32);
        }

        const int rk = 32 * wd + lm, rv = 32 * wm + lm;
        #pragma unroll
        for (int m = 0; m < 4; ++m) {
            const int sa = ((2 * m + lh) ^ (lm & 7) ^ (lm >> 2)) & 7;
            bf16x8 af = *(const bf16x8*)&Kb[buf][rk][sa * 4];
            bf16x8 bv = *(const bf16x8*)&Vb[buf][rv][sa * 4];
            acc = __builtin_amdgcn_mfma_f32_32x32x16_bf16(af, bv, acc, 0, 0, 0);
        }
    }

    float* dst = pkv + (size_t)blk * (E_ * E_);
    #pragma unroll
    for (int r = 0; r < 16; ++r) {
        const int ro = (r & 3) + 8 * (r >> 2) + 4 * lh;
        dst[(32 * wd + ro) * E_ + 32 * wm + lm] = acc[r];
    }

    __syncthreads();
    float* ksb = (float*)&Kb[0][0][0];     // [256][8] f32 = 8 KB
    *(float4*)&ksb[t * 8]     = make_float4(ksp[0], ksp[1], ksp[2], ksp[3]);
    *(float4*)&ksb[t * 8 + 4] = make_float4(ksp[4], ksp[5], ksp[6], ksp[7]);
    __syncthreads();
    if (t < E_) {
        const int cc = (t & 31) >> 2, e = (t >> 5) * 4 + (t & 3);
        float s = 0.f;
        #pragma unroll
        for (int pp = 0; pp < 32; ++pp) s += ksb[(pp * 8 + cc) * 8 + e];
        pks[(size_t)blk * E_ + t] = s;
    }
}

// ---------------------------------------------------------------------------
// PROBE 1 (fixed): dense grid-stride float4 sweep of k+v.
// Each array is 4,194,304 float4 (67 MB); 2048 blocks x 256 thr x 8 iters
// covers each array EXACTLY once. (r13 crash: 16 iters = 2x overrun.)
// ---------------------------------------------------------------------------
#define PDB_ 2048
__global__ __launch_bounds__(256) void probe_dense(
    const float* __restrict__ a, const float* __restrict__ b,
    float* __restrict__ o)
{
    const size_t tid = (size_t)blockIdx.x * 256 + threadIdx.x;
    const float4* A = (const float4*)a;
    const float4* B = (const float4*)b;
    float s = 0.f;
    #pragma unroll
    for (int i = 0; i < 8; ++i) {
        float4 x = A[tid + (size_t)i * (PDB_ * 256)];
        float4 y = B[tid + (size_t)i * (PDB_ * 256)];
        s += x.x + x.y + x.z + x.w + y.x + y.y + y.z + y.w;
    }
    o[tid] = s;
}

// ---------------------------------------------------------------------------
// PROBE 2: la_kv's EXACT address multiset (h-sliced 256 B per 2 KB row),
// zero LDS/barrier/MFMA/featmap. 1024 blocks x 256 thr, 32 loads fully
// unrolled. (Addressing bounds-checked: max row 8191.)
// ---------------------------------------------------------------------------
__global__ __launch_bounds__(256) void probe_sliced(
    const float* __restrict__ keys, const float* __restrict__ values,
    float* __restrict__ o)
{
    const int blk = blockIdx.x;
    const int nh = blk / SPLIT_, chunk = blk % SPLIT_;
    const int n = nh / H_, h = nh % H_;
    const int t = threadIdx.x;
    const int pr = t >> 3, c = t & 7;
    const size_t base = (size_t)n * (L_ * H_ * E_) + (size_t)h * E_;
    const size_t rbase = base + (size_t)(chunk * RPB_ + 2 * pr) * STRIDE_ + 4 * c;
    float s = 0.f;
    #pragma unroll
    for (int ch = 0; ch < NCHK_; ++ch) {
        const size_t nb = rbase + (size_t)ch * CHR_ * STRIDE_;
        float4 k0 = *(const float4*)(keys + nb);
        float4 k1 = *(const float4*)(keys + nb + 32);
        float4 k2 = *(const float4*)(keys + nb + STRIDE_);
        float4 k3 = *(const float4*)(keys + nb + STRIDE_ + 32);
        float4 v0 = *(const float4*)(values + nb);
        float4 v1 = *(const float4*)(values + nb + 32);
        float4 v2 = *(const float4*)(values + nb + STRIDE_);
        float4 v3 = *(const float4*)(values + nb + STRIDE_ + 32);
        s += k0.x+k0.y+k0.z+k0.w + k1.x+k1.y+k1.z+k1.w
           + k2.x+k2.y+k2.z+k2.w + k3.x+k3.y+k3.z+k3.w
           + v0.x+v0.y+v0.z+v0.w + v1.x+v1.y+v1.z+v1.w
           + v2.x+v2.y+v2.z+v2.w + v3.x+v3.y+v3.z+v3.w;
    }
    o[(size_t)blk * 256 + t] = s;
}

// ---------------------------------------------------------------------------
// Reduce (r12 verbatim).
// ---------------------------------------------------------------------------
__global__ __launch_bounds__(256) void la_reduce(
    const float* __restrict__ pkv, const float* __restrict__ pks,
    unsigned short* __restrict__ kvt, float* __restrict__ ksum)
{
    const int b = blockIdx.x, nh = b >> 4, sl = b & 15;
    const int e = sl * 256 + threadIdx.x;          // e = d*64 + m
    const float* src = pkv + (size_t)nh * SPLIT_ * (E_ * E_) + e;
    float s = 0.f;
    #pragma unroll
    for (int c = 0; c < SPLIT_; ++c) s += src[(size_t)c * (E_ * E_)];
    const int d = e >> 6, m = e & 63;
    kvt[(size_t)nh * (E_ * E_) + m * E_ + d] = f2bf(s);

    if (sl == 0 && threadIdx.x < E_) {
        const float* sp = pks + (size_t)nh * SPLIT_ * E_ + threadIdx.x;
        float ss = 0.f;
        #pragma unroll
        for (int c = 0; c < SPLIT_; ++c) ss += sp[c * E_];
        ksum[nh * E_ + threadIdx.x] = ss;
    }
}

// ---------------------------------------------------------------------------
// Phase 2 (r12 verbatim).
// ---------------------------------------------------------------------------
__global__ __launch_bounds__(256) void la_out(
    const float* __restrict__ q, const unsigned short* __restrict__ kvt,
    const float* __restrict__ ksum, float* __restrict__ out)
{
    const int blk = blockIdx.x, nh = blk >> 5, tile = blk & 31;
    const int n = nh / H_, h = nh % H_;
    const int t = threadIdx.x, l = t & 63, w = t >> 6;
    const int lm = l & 31, lh = l >> 5;

    __shared__ float zbuf[4][32];

    const unsigned short* kb = kvt + (size_t)nh * (E_ * E_);
    const float* ks = ksum + nh * E_;

    bf16x8 bfr[4][2];
    float4 kr[4][2];
    #pragma unroll
    for (int st = 0; st < 4; ++st) {
        #pragma unroll
        for (int c = 0; c < 2; ++c)
            bfr[st][c] = *(const bf16x8*)&kb[(32 * c + lm) * E_ + st * 16 + 8 * lh];
        kr[st][0] = *(const float4*)&ks[st * 16 + 8 * lh];
        kr[st][1] = *(const float4*)&ks[st * 16 + 8 * lh + 4];
    }

    const size_t base = (size_t)n * (L_ * H_ * E_) + (size_t)h * E_;

    #pragma unroll
    for (int bnd = 0; bnd < 2; ++bnd) {
        const int l0 = tile * 256 + w * 64 + bnd * 32;
        const float* qp = q + base + (size_t)(l0 + lm) * STRIDE_ + 8 * lh;

        float4 qa[4], qb[4];
        #pragma unroll
        for (int st = 0; st < 4; ++st) {
            qa[st] = *(const float4*)(qp + st * 16);
            qb[st] = *(const float4*)(qp + st * 16 + 4);
        }

        float zd = 0.f;
        bf16x8 af[4];
        #pragma unroll
        for (int st = 0; st < 4; ++st) {
            const float f0 = featmap(qa[st].x), f1 = featmap(qa[st].y),
                        f2 = featmap(qa[st].z), f3 = featmap(qa[st].w);
            const float g0 = featmap(qb[st].x), g1 = featmap(qb[st].y),
                        g2 = featmap(qb[st].z), g3 = featmap(qb[st].w);
            zd += f0 * kr[st][0].x + f1 * kr[st][0].y + f2 * kr[st][0].z + f3 * kr[st][0].w
                + g0 * kr[st][1].x + g1 * kr[st][1].y + g2 * kr[st][1].z + g3 * kr[st][1].w;
            union { bf16x8 v; unsigned u[4]; } a;
            a.u[0] = cvt_pk_bf16(f0, f1);
            a.u[1] = cvt_pk_bf16(f2, f3);
            a.u[2] = cvt_pk_bf16(g0, g1);
            a.u[3] = cvt_pk_bf16(g2, g3);
            af[st] = a.v;
        }
        zd += __shfl_xor(zd, 32);
        const float z = 1.0f / (zd + 1e-6f);
        if (l < 32) zbuf[w][l] = z;
        __builtin_amdgcn_wave_barrier();

        f32x16 c0 = {0,0,0,0,0,0,0,0,0,0,0,0,0,0,0,0};
        f32x16 c1 = {0,0,0,0,0,0,0,0,0,0,0,0,0,0,0,0};
        #pragma unroll
        for (int st = 0; st < 4; ++st) {
            c0 = __builtin_amdgcn_mfma_f32_32x32x16_bf16(af[st], bfr[st][0], c0, 0, 0, 0);
            c1 = __builtin_amdgcn_mfma_f32_32x32x16_bf16(af[st], bfr[st][1], c1, 0, 0, 0);
        }

        float* op = out + base + (size_t)l0 * STRIDE_ + lm;
        #pragma unroll
        for (int r = 0; r < 16; ++r) {
            const int ro = (r & 3) + 8 * (r >> 2) + 4 * lh;
            const float zz = zbuf[w][ro];
            op[(size_t)ro * STRIDE_]      = c0[r] * zz;
            op[(size_t)ro * STRIDE_ + 32] = c1[r] * zz;
        }
        __builtin_amdgcn_wave_barrier();   // zbuf reused next band
    }
}

extern "C" void kernel_launch(void* const* d_in, const int* in_sizes, int n_in,
                              void* d_out, int out_size, void* d_ws, size_t ws_size,
                              hipStream_t stream) {
    (void)in_sizes; (void)n_in; (void)out_size; (void)ws_size;
    const float* qq = (const float*)d_in[0];
    const float* kk = (const float*)d_in[1];
    const float* vv = (const float*)d_in[2];
    float* outp = (float*)d_out;
    float* ws   = (float*)d_ws;

    float* pkv = ws;
    float* pks = ws + (size_t)NH_ * SPLIT_ * (E_ * E_);
    unsigned short* kvt = (unsigned short*)(pks + (size_t)NH_ * SPLIT_ * E_);
    float* ksm = (float*)(kvt + (size_t)NH_ * (E_ * E_));
    float* pscr0 = ws + 5000000;    // probe scratch (20 MB mark, dead region)
    float* pscr1 = ws + 5600000;

    la_kv<<<NH_ * SPLIT_, 256, 0, stream>>>(kk, vv, pkv, pks);
    probe_dense<<<PDB_, 256, 0, stream>>>(kk, vv, pscr0);
    probe_sliced<<<NH_ * SPLIT_, 256, 0, stream>>>(kk, vv, pscr1);
    la_reduce<<<NH_ * 16, 256, 0, stream>>>(pkv, pks, kvt, ksm);
    la_out<<<NH_ * 32, 256, 0, stream>>>(qq, kvt, ksm, outp);
}

// Round 15
// 85.049 us; speedup vs baseline: 1.2318x; 1.2318x over previous
//
#include <hip/hip_runtime.h>

// n=4, L=8192, h=8, e=64, fp32 in/out
#define N_      4
#define L_      8192
#define H_      8
#define E_      64
#define NH_     (N_ * H_)
#define STRIDE_ (H_ * E_)          // 512 floats between rows
#define CHR_    64                 // rows per staged chunk (swizzle needs 64)

typedef short bf16x8 __attribute__((ext_vector_type(8)));
typedef float f32x16 __attribute__((ext_vector_type(16)));

__device__ __forceinline__ float featmap(float x) {
    float xs = x * 0.35355339059327373f;   // * 64^-0.25
    return xs > 0.0f ? xs + 1.0f : __expf(xs);
}
__device__ __forceinline__ unsigned short f2bf(float f) {   // RNE f32->bf16
    union { float f; unsigned u; } c{f};
    unsigned r = c.u + 0x7FFFu + ((c.u >> 16) & 1u);
    return (unsigned short)(r >> 16);
}
__device__ __forceinline__ unsigned cvt_pk_bf16(float lo, float hi) {
    unsigned r;
    asm("v_cvt_pk_bf16_f32 %0, %1, %2" : "=v"(r) : "v"(lo), "v"(hi));
    return r;
}
__device__ __forceinline__ int swz_slot(int d, int sp4) {   // sp4 = sp>>2
    return (sp4 ^ (d & 7) ^ ((d >> 2) & 7)) & 7;
}

// ---------------------------------------------------------------------------
// Phase 1 (r12 body VERBATIM, templated on SPLIT).
// SPLIT=64: 2048 blocks x 2 chunk-iterations -- halves each block's serial
// barrier-separated critical path and doubles block-level parallelism (the
// only latency-hiding units that never convoy on a common barrier).
// Swizzle requires CHR=64 (slot() must span all 8 b128 slots) -- unchanged.
// ---------------------------------------------------------------------------
template <int SPLIT>
__global__ __launch_bounds__(256) void la_kv(
    const float* __restrict__ keys, const float* __restrict__ values,
    float* __restrict__ pkv, float* __restrict__ pks)
{
    constexpr int RPB  = L_ / SPLIT;     // rows per block
    constexpr int NCHK = RPB / CHR_;     // chunk iterations

    const int blk = blockIdx.x;
    const int nh = blk / SPLIT, chunk = blk % SPLIT;
    const int n = nh / H_, h = nh % H_;
    const int t = threadIdx.x, l = t & 63;
    const int w = t >> 6, wd = w >> 1, wm = w & 1;
    const int lm = l & 31, lh = l >> 5;
    const int pr = t >> 3, c = t & 7;      // row-pair 0..31, col-octet 0..7

    __shared__ unsigned Kb[2][CHR_][32];   // [buf][d][swizzled s-pair] 16 KB
    __shared__ unsigned Vb[2][CHR_][32];   // 16 KB

    f32x16 acc = {0,0,0,0,0,0,0,0,0,0,0,0,0,0,0,0};
    float ksp[8] = {0.f,0.f,0.f,0.f,0.f,0.f,0.f,0.f};

    const size_t base = (size_t)n * (L_ * H_ * E_) + (size_t)h * E_;
    const size_t rbase = base + (size_t)(chunk * RPB + 2 * pr) * STRIDE_ + 4 * c;

    float4 kr0 = *(const float4*)(keys + rbase);
    float4 kr1 = *(const float4*)(keys + rbase + 32);
    float4 kr2 = *(const float4*)(keys + rbase + STRIDE_);
    float4 kr3 = *(const float4*)(keys + rbase + STRIDE_ + 32);
    float4 vr0 = *(const float4*)(values + rbase);
    float4 vr1 = *(const float4*)(values + rbase + 32);
    float4 vr2 = *(const float4*)(values + rbase + STRIDE_);
    float4 vr3 = *(const float4*)(values + rbase + STRIDE_ + 32);

    #pragma unroll
    for (int ch = 0; ch < NCHK; ++ch) {
        const int buf = ch & 1;
        float a0[4] = {kr0.x, kr0.y, kr0.z, kr0.w};
        float a1[4] = {kr1.x, kr1.y, kr1.z, kr1.w};
        float a2[4] = {kr2.x, kr2.y, kr2.z, kr2.w};
        float a3[4] = {kr3.x, kr3.y, kr3.z, kr3.w};
        float b0[4] = {vr0.x, vr0.y, vr0.z, vr0.w};
        float b1[4] = {vr1.x, vr1.y, vr1.z, vr1.w};
        float b2[4] = {vr2.x, vr2.y, vr2.z, vr2.w};
        float b3[4] = {vr3.x, vr3.y, vr3.z, vr3.w};

        #pragma unroll
        for (int i = 0; i < 4; ++i) {
            const float f0 = featmap(a0[i]), f1 = featmap(a1[i]);
            const float f2 = featmap(a2[i]), f3 = featmap(a3[i]);
            ksp[i]     += f0 + f2;
            ksp[4 + i] += f1 + f3;
            const int dl = 4 * c + i, dh = 32 + 4 * c + i;
            const int wl = swz_slot(dl, pr >> 2) * 4 + (pr & 3);
            const int wh = swz_slot(dh, pr >> 2) * 4 + (pr & 3);
            Kb[buf][dl][wl] = cvt_pk_bf16(f0, f2);      // lo = even s
            Kb[buf][dh][wh] = cvt_pk_bf16(f1, f3);
            Vb[buf][dl][wl] = cvt_pk_bf16(b0[i], b2[i]);
            Vb[buf][dh][wh] = cvt_pk_bf16(b1[i], b3[i]);
        }

        __syncthreads();   // free drain: loads already consumed by the stores

        if (ch + 1 < NCHK) {               // issue next chunk's loads NOW
            const size_t nb = rbase + (size_t)(ch + 1) * CHR_ * STRIDE_;
            kr0 = *(const float4*)(keys + nb);
            kr1 = *(const float4*)(keys + nb + 32);
            kr2 = *(const float4*)(keys + nb + STRIDE_);
            kr3 = *(const float4*)(keys + nb + STRIDE_ + 32);
            vr0 = *(const float4*)(values + nb);
            vr1 = *(const float4*)(values + nb + 32);
            vr2 = *(const float4*)(values + nb + STRIDE_);
            vr3 = *(const float4*)(values + nb + STRIDE_ + 32);
        }

        const int rk = 32 * wd + lm, rv = 32 * wm + lm;
        #pragma unroll
        for (int m = 0; m < 4; ++m) {
            const int sa = ((2 * m + lh) ^ (lm & 7) ^ (lm >> 2)) & 7;
            bf16x8 af = *(const bf16x8*)&Kb[buf][rk][sa * 4];
            bf16x8 bv = *(const bf16x8*)&Vb[buf][rv][sa * 4];
            acc = __builtin_amdgcn_mfma_f32_32x32x16_bf16(af, bv, acc, 0, 0, 0);
        }
    }

    // C/D layout (m74/m101): col=lane&31, row=(r&3)+8*(r>>2)+4*(lane>>5)
    float* dst = pkv + (size_t)blk * (E_ * E_);
    #pragma unroll
    for (int r = 0; r < 16; ++r) {
        const int ro = (r & 3) + 8 * (r >> 2) + 4 * lh;
        dst[(32 * wd + ro) * E_ + 32 * wm + lm] = acc[r];
    }

    // ksum: per-thread partials [8] -> LDS scratch (reuse Kb[0]) -> reduce
    __syncthreads();
    float* ksb = (float*)&Kb[0][0][0];     // [256][8] f32 = 8 KB
    *(float4*)&ksb[t * 8]     = make_float4(ksp[0], ksp[1], ksp[2], ksp[3]);
    *(float4*)&ksb[t * 8 + 4] = make_float4(ksp[4], ksp[5], ksp[6], ksp[7]);
    __syncthreads();
    if (t < E_) {
        const int cc = (t & 31) >> 2, e = (t >> 5) * 4 + (t & 3);
        float s = 0.f;
        #pragma unroll
        for (int pp = 0; pp < 32; ++pp) s += ksb[(pp * 8 + cc) * 8 + e];
        pks[(size_t)blk * E_ + t] = s;
    }
}

// ---------------------------------------------------------------------------
// Reduce: KV[d][m] = sum_c pkv; emit KV^T bf16 [m][d] + ksum f32.
// ---------------------------------------------------------------------------
template <int SPLIT>
__global__ __launch_bounds__(256) void la_reduce(
    const float* __restrict__ pkv, const float* __restrict__ pks,
    unsigned short* __restrict__ kvt, float* __restrict__ ksum)
{
    const int b = blockIdx.x, nh = b >> 4, sl = b & 15;
    const int e = sl * 256 + threadIdx.x;          // e = d*64 + m
    const float* src = pkv + (size_t)nh * SPLIT * (E_ * E_) + e;
    float s = 0.f;
    #pragma unroll
    for (int c = 0; c < SPLIT; ++c) s += src[(size_t)c * (E_ * E_)];
    const int d = e >> 6, m = e & 63;
    kvt[(size_t)nh * (E_ * E_) + m * E_ + d] = f2bf(s);

    if (sl == 0 && threadIdx.x < E_) {
        const float* sp = pks + (size_t)nh * SPLIT * E_ + threadIdx.x;
        float ss = 0.f;
        #pragma unroll
        for (int c = 0; c < SPLIT; ++c) ss += sp[c * E_];
        ksum[nh * E_ + threadIdx.x] = ss;
    }
}

// ---------------------------------------------------------------------------
// Phase 2: out[l][m] = z[l] * sum_d qf[l,d]*KV[d,m] via MFMA (r12 verbatim).
// ---------------------------------------------------------------------------
__global__ __launch_bounds__(256) void la_out(
    const float* __restrict__ q, const unsigned short* __restrict__ kvt,
    const float* __restrict__ ksum, float* __restrict__ out)
{
    const int blk = blockIdx.x, nh = blk >> 5, tile = blk & 31;
    const int n = nh / H_, h = nh % H_;
    const int t = threadIdx.x, l = t & 63, w = t >> 6;
    const int lm = l & 31, lh = l >> 5;

    __shared__ float zbuf[4][32];

    const unsigned short* kb = kvt + (size_t)nh * (E_ * E_);
    const float* ks = ksum + nh * E_;

    bf16x8 bfr[4][2];
    float4 kr[4][2];
    #pragma unroll
    for (int st = 0; st < 4; ++st) {
        #pragma unroll
        for (int c = 0; c < 2; ++c)
            bfr[st][c] = *(const bf16x8*)&kb[(32 * c + lm) * E_ + st * 16 + 8 * lh];
        kr[st][0] = *(const float4*)&ks[st * 16 + 8 * lh];
        kr[st][1] = *(const float4*)&ks[st * 16 + 8 * lh + 4];
    }

    const size_t base = (size_t)n * (L_ * H_ * E_) + (size_t)h * E_;

    #pragma unroll
    for (int bnd = 0; bnd < 2; ++bnd) {
        const int l0 = tile * 256 + w * 64 + bnd * 32;
        const float* qp = q + base + (size_t)(l0 + lm) * STRIDE_ + 8 * lh;

        float4 qa[4], qb[4];
        #pragma unroll
        for (int st = 0; st < 4; ++st) {
            qa[st] = *(const float4*)(qp + st * 16);
            qb[st] = *(const float4*)(qp + st * 16 + 4);
        }

        float zd = 0.f;
        bf16x8 af[4];
        #pragma unroll
        for (int st = 0; st < 4; ++st) {
            const float f0 = featmap(qa[st].x), f1 = featmap(qa[st].y),
                        f2 = featmap(qa[st].z), f3 = featmap(qa[st].w);
            const float g0 = featmap(qb[st].x), g1 = featmap(qb[st].y),
                        g2 = featmap(qb[st].z), g3 = featmap(qb[st].w);
            zd += f0 * kr[st][0].x + f1 * kr[st][0].y + f2 * kr[st][0].z + f3 * kr[st][0].w
                + g0 * kr[st][1].x + g1 * kr[st][1].y + g2 * kr[st][1].z + g3 * kr[st][1].w;
            union { bf16x8 v; unsigned u[4]; } a;
            a.u[0] = cvt_pk_bf16(f0, f1);
            a.u[1] = cvt_pk_bf16(f2, f3);
            a.u[2] = cvt_pk_bf16(g0, g1);
            a.u[3] = cvt_pk_bf16(g2, g3);
            af[st] = a.v;
        }
        zd += __shfl_xor(zd, 32);
        const float z = 1.0f / (zd + 1e-6f);
        if (l < 32) zbuf[w][l] = z;
        __builtin_amdgcn_wave_barrier();

        f32x16 c0 = {0,0,0,0,0,0,0,0,0,0,0,0,0,0,0,0};
        f32x16 c1 = {0,0,0,0,0,0,0,0,0,0,0,0,0,0,0,0};
        #pragma unroll
        for (int st = 0; st < 4; ++st) {
            c0 = __builtin_amdgcn_mfma_f32_32x32x16_bf16(af[st], bfr[st][0], c0, 0, 0, 0);
            c1 = __builtin_amdgcn_mfma_f32_32x32x16_bf16(af[st], bfr[st][1], c1, 0, 0, 0);
        }

        float* op = out + base + (size_t)l0 * STRIDE_ + lm;
        #pragma unroll
        for (int r = 0; r < 16; ++r) {
            const int ro = (r & 3) + 8 * (r >> 2) + 4 * lh;
            const float zz = zbuf[w][ro];
            op[(size_t)ro * STRIDE_]      = c0[r] * zz;
            op[(size_t)ro * STRIDE_ + 32] = c1[r] * zz;
        }
        __builtin_amdgcn_wave_barrier();   // zbuf reused next band
    }
}

// ws layout (floats): pkv[NH*SPLIT][4096] | pks[NH*SPLIT][64] |
//                     kvt bf16 (float-sized area) | ksum[NH][64]
static inline size_t ws_need_floats(int split) {
    return (size_t)NH_ * split * (E_ * E_) + (size_t)NH_ * split * E_
         + (size_t)NH_ * (E_ * E_) / 2 + (size_t)NH_ * E_;
}

extern "C" void kernel_launch(void* const* d_in, const int* in_sizes, int n_in,
                              void* d_out, int out_size, void* d_ws, size_t ws_size,
                              hipStream_t stream) {
    (void)in_sizes; (void)n_in; (void)out_size;
    const float* qq = (const float*)d_in[0];
    const float* kk = (const float*)d_in[1];
    const float* vv = (const float*)d_in[2];
    float* outp = (float*)d_out;
    float* ws   = (float*)d_ws;

    const int split = (ws_size >= ws_need_floats(64) * sizeof(float)) ? 64 : 32;

    float* pkv = ws;
    float* pks = ws + (size_t)NH_ * split * (E_ * E_);
    unsigned short* kvt = (unsigned short*)(pks + (size_t)NH_ * split * E_);
    float* ksm = (float*)(kvt + (size_t)NH_ * (E_ * E_));

    if (split == 64) {
        la_kv<64><<<NH_ * 64, 256, 0, stream>>>(kk, vv, pkv, pks);
        la_reduce<64><<<NH_ * 16, 256, 0, stream>>>(pkv, pks, kvt, ksm);
    } else {
        la_kv<32><<<NH_ * 32, 256, 0, stream>>>(kk, vv, pkv, pks);
        la_reduce<32><<<NH_ * 16, 256, 0, stream>>>(pkv, pks, kvt, ksm);
    }
    la_out<<<NH_ * 32, 256, 0, stream>>>(qq, kvt, ksm, outp);
}

// Round 16
// 62.795 us; speedup vs baseline: 1.6683x; 1.3544x over previous
//
#include <hip/hip_runtime.h>

// n=4, L=8192, h=8, e=64, fp32 in/out
#define N_      4
#define L_      8192
#define H_      8
#define E_      64
#define NH_     (N_ * H_)
#define STRIDE_ (H_ * E_)          // 512 floats between rows
#define CHR_    64                 // rows per staged chunk (swizzle needs 64)

typedef short bf16x8 __attribute__((ext_vector_type(8)));
typedef float f32x16 __attribute__((ext_vector_type(16)));

__device__ __forceinline__ float featmap(float x) {
    float xs = x * 0.35355339059327373f;   // * 64^-0.25
    return xs > 0.0f ? xs + 1.0f : __expf(xs);
}
__device__ __forceinline__ unsigned short f2bf(float f) {   // RNE f32->bf16
    union { float f; unsigned u; } c{f};
    unsigned r = c.u + 0x7FFFu + ((c.u >> 16) & 1u);
    return (unsigned short)(r >> 16);
}
__device__ __forceinline__ unsigned cvt_pk_bf16(float lo, float hi) {
    unsigned r;
    asm("v_cvt_pk_bf16_f32 %0, %1, %2" : "=v"(r) : "v"(lo), "v"(hi));
    return r;
}
__device__ __forceinline__ int swz_slot(int d, int sp4) {   // sp4 = sp>>2
    return (sp4 ^ (d & 7) ^ ((d >> 2) & 7)) & 7;
}

// ---------------------------------------------------------------------------
// Phase 1 (r12 body VERBATIM, templated on SPLIT).
// SPLIT=16: 512 blocks x 8 chunk-iterations. Rationale (r15 evidence):
// SPLIT=64 regressed (partial traffic dominates; block count is NOT the
// limiter), so go the other way -- longer per-block pipelines amortize the
// full-latency prologue (now 1/8 of block life instead of 1/4), pkv traffic
// halves to 8.4 MB, and 512 blocks = exactly 2 blocks/CU with zero tail.
// ---------------------------------------------------------------------------
template <int SPLIT>
__global__ __launch_bounds__(256) void la_kv(
    const float* __restrict__ keys, const float* __restrict__ values,
    float* __restrict__ pkv, float* __restrict__ pks)
{
    constexpr int RPB  = L_ / SPLIT;     // rows per block
    constexpr int NCHK = RPB / CHR_;     // chunk iterations

    const int blk = blockIdx.x;
    const int nh = blk / SPLIT, chunk = blk % SPLIT;
    const int n = nh / H_, h = nh % H_;
    const int t = threadIdx.x, l = t & 63;
    const int w = t >> 6, wd = w >> 1, wm = w & 1;
    const int lm = l & 31, lh = l >> 5;
    const int pr = t >> 3, c = t & 7;      // row-pair 0..31, col-octet 0..7

    __shared__ unsigned Kb[2][CHR_][32];   // [buf][d][swizzled s-pair] 16 KB
    __shared__ unsigned Vb[2][CHR_][32];   // 16 KB

    f32x16 acc = {0,0,0,0,0,0,0,0,0,0,0,0,0,0,0,0};
    float ksp[8] = {0.f,0.f,0.f,0.f,0.f,0.f,0.f,0.f};

    const size_t base = (size_t)n * (L_ * H_ * E_) + (size_t)h * E_;
    const size_t rbase = base + (size_t)(chunk * RPB + 2 * pr) * STRIDE_ + 4 * c;

    float4 kr0 = *(const float4*)(keys + rbase);
    float4 kr1 = *(const float4*)(keys + rbase + 32);
    float4 kr2 = *(const float4*)(keys + rbase + STRIDE_);
    float4 kr3 = *(const float4*)(keys + rbase + STRIDE_ + 32);
    float4 vr0 = *(const float4*)(values + rbase);
    float4 vr1 = *(const float4*)(values + rbase + 32);
    float4 vr2 = *(const float4*)(values + rbase + STRIDE_);
    float4 vr3 = *(const float4*)(values + rbase + STRIDE_ + 32);

    #pragma unroll
    for (int ch = 0; ch < NCHK; ++ch) {
        const int buf = ch & 1;
        float a0[4] = {kr0.x, kr0.y, kr0.z, kr0.w};
        float a1[4] = {kr1.x, kr1.y, kr1.z, kr1.w};
        float a2[4] = {kr2.x, kr2.y, kr2.z, kr2.w};
        float a3[4] = {kr3.x, kr3.y, kr3.z, kr3.w};
        float b0[4] = {vr0.x, vr0.y, vr0.z, vr0.w};
        float b1[4] = {vr1.x, vr1.y, vr1.z, vr1.w};
        float b2[4] = {vr2.x, vr2.y, vr2.z, vr2.w};
        float b3[4] = {vr3.x, vr3.y, vr3.z, vr3.w};

        #pragma unroll
        for (int i = 0; i < 4; ++i) {
            const float f0 = featmap(a0[i]), f1 = featmap(a1[i]);
            const float f2 = featmap(a2[i]), f3 = featmap(a3[i]);
            ksp[i]     += f0 + f2;
            ksp[4 + i] += f1 + f3;
            const int dl = 4 * c + i, dh = 32 + 4 * c + i;
            const int wl = swz_slot(dl, pr >> 2) * 4 + (pr & 3);
            const int wh = swz_slot(dh, pr >> 2) * 4 + (pr & 3);
            Kb[buf][dl][wl] = cvt_pk_bf16(f0, f2);      // lo = even s
            Kb[buf][dh][wh] = cvt_pk_bf16(f1, f3);
            Vb[buf][dl][wl] = cvt_pk_bf16(b0[i], b2[i]);
            Vb[buf][dh][wh] = cvt_pk_bf16(b1[i], b3[i]);
        }

        __syncthreads();   // free drain: loads already consumed by the stores

        if (ch + 1 < NCHK) {               // issue next chunk's loads NOW
            const size_t nb = rbase + (size_t)(ch + 1) * CHR_ * STRIDE_;
            kr0 = *(const float4*)(keys + nb);
            kr1 = *(const float4*)(keys + nb + 32);
            kr2 = *(const float4*)(keys + nb + STRIDE_);
            kr3 = *(const float4*)(keys + nb + STRIDE_ + 32);
            vr0 = *(const float4*)(values + nb);
            vr1 = *(const float4*)(values + nb + 32);
            vr2 = *(const float4*)(values + nb + STRIDE_);
            vr3 = *(const float4*)(values + nb + STRIDE_ + 32);
        }

        const int rk = 32 * wd + lm, rv = 32 * wm + lm;
        #pragma unroll
        for (int m = 0; m < 4; ++m) {
            const int sa = ((2 * m + lh) ^ (lm & 7) ^ (lm >> 2)) & 7;
            bf16x8 af = *(const bf16x8*)&Kb[buf][rk][sa * 4];
            bf16x8 bv = *(const bf16x8*)&Vb[buf][rv][sa * 4];
            acc = __builtin_amdgcn_mfma_f32_32x32x16_bf16(af, bv, acc, 0, 0, 0);
        }
    }

    // C/D layout (m74/m101): col=lane&31, row=(r&3)+8*(r>>2)+4*(lane>>5)
    float* dst = pkv + (size_t)blk * (E_ * E_);
    #pragma unroll
    for (int r = 0; r < 16; ++r) {
        const int ro = (r & 3) + 8 * (r >> 2) + 4 * lh;
        dst[(32 * wd + ro) * E_ + 32 * wm + lm] = acc[r];
    }

    // ksum: per-thread partials [8] -> LDS scratch (reuse Kb[0]) -> reduce
    __syncthreads();
    float* ksb = (float*)&Kb[0][0][0];     // [256][8] f32 = 8 KB
    *(float4*)&ksb[t * 8]     = make_float4(ksp[0], ksp[1], ksp[2], ksp[3]);
    *(float4*)&ksb[t * 8 + 4] = make_float4(ksp[4], ksp[5], ksp[6], ksp[7]);
    __syncthreads();
    if (t < E_) {
        const int cc = (t & 31) >> 2, e = (t >> 5) * 4 + (t & 3);
        float s = 0.f;
        #pragma unroll
        for (int pp = 0; pp < 32; ++pp) s += ksb[(pp * 8 + cc) * 8 + e];
        pks[(size_t)blk * E_ + t] = s;
    }
}

// ---------------------------------------------------------------------------
// Reduce: KV[d][m] = sum_c pkv; emit KV^T bf16 [m][d] + ksum f32.
// ---------------------------------------------------------------------------
template <int SPLIT>
__global__ __launch_bounds__(256) void la_reduce(
    const float* __restrict__ pkv, const float* __restrict__ pks,
    unsigned short* __restrict__ kvt, float* __restrict__ ksum)
{
    const int b = blockIdx.x, nh = b >> 4, sl = b & 15;
    const int e = sl * 256 + threadIdx.x;          // e = d*64 + m
    const float* src = pkv + (size_t)nh * SPLIT * (E_ * E_) + e;
    float s = 0.f;
    #pragma unroll
    for (int c = 0; c < SPLIT; ++c) s += src[(size_t)c * (E_ * E_)];
    const int d = e >> 6, m = e & 63;
    kvt[(size_t)nh * (E_ * E_) + m * E_ + d] = f2bf(s);

    if (sl == 0 && threadIdx.x < E_) {
        const float* sp = pks + (size_t)nh * SPLIT * E_ + threadIdx.x;
        float ss = 0.f;
        #pragma unroll
        for (int c = 0; c < SPLIT; ++c) ss += sp[c * E_];
        ksum[nh * E_ + threadIdx.x] = ss;
    }
}

// ---------------------------------------------------------------------------
// Phase 2: out[l][m] = z[l] * sum_d qf[l,d]*KV[d,m] via MFMA (r12 verbatim).
// ---------------------------------------------------------------------------
__global__ __launch_bounds__(256) void la_out(
    const float* __restrict__ q, const unsigned short* __restrict__ kvt,
    const float* __restrict__ ksum, float* __restrict__ out)
{
    const int blk = blockIdx.x, nh = blk >> 5, tile = blk & 31;
    const int n = nh / H_, h = nh % H_;
    const int t = threadIdx.x, l = t & 63, w = t >> 6;
    const int lm = l & 31, lh = l >> 5;

    __shared__ float zbuf[4][32];

    const unsigned short* kb = kvt + (size_t)nh * (E_ * E_);
    const float* ks = ksum + nh * E_;

    bf16x8 bfr[4][2];
    float4 kr[4][2];
    #pragma unroll
    for (int st = 0; st < 4; ++st) {
        #pragma unroll
        for (int c = 0; c < 2; ++c)
            bfr[st][c] = *(const bf16x8*)&kb[(32 * c + lm) * E_ + st * 16 + 8 * lh];
        kr[st][0] = *(const float4*)&ks[st * 16 + 8 * lh];
        kr[st][1] = *(const float4*)&ks[st * 16 + 8 * lh + 4];
    }

    const size_t base = (size_t)n * (L_ * H_ * E_) + (size_t)h * E_;

    #pragma unroll
    for (int bnd = 0; bnd < 2; ++bnd) {
        const int l0 = tile * 256 + w * 64 + bnd * 32;
        const float* qp = q + base + (size_t)(l0 + lm) * STRIDE_ + 8 * lh;

        float4 qa[4], qb[4];
        #pragma unroll
        for (int st = 0; st < 4; ++st) {
            qa[st] = *(const float4*)(qp + st * 16);
            qb[st] = *(const float4*)(qp + st * 16 + 4);
        }

        float zd = 0.f;
        bf16x8 af[4];
        #pragma unroll
        for (int st = 0; st < 4; ++st) {
            const float f0 = featmap(qa[st].x), f1 = featmap(qa[st].y),
                        f2 = featmap(qa[st].z), f3 = featmap(qa[st].w);
            const float g0 = featmap(qb[st].x), g1 = featmap(qb[st].y),
                        g2 = featmap(qb[st].z), g3 = featmap(qb[st].w);
            zd += f0 * kr[st][0].x + f1 * kr[st][0].y + f2 * kr[st][0].z + f3 * kr[st][0].w
                + g0 * kr[st][1].x + g1 * kr[st][1].y + g2 * kr[st][1].z + g3 * kr[st][1].w;
            union { bf16x8 v; unsigned u[4]; } a;
            a.u[0] = cvt_pk_bf16(f0, f1);
            a.u[1] = cvt_pk_bf16(f2, f3);
            a.u[2] = cvt_pk_bf16(g0, g1);
            a.u[3] = cvt_pk_bf16(g2, g3);
            af[st] = a.v;
        }
        zd += __shfl_xor(zd, 32);
        const float z = 1.0f / (zd + 1e-6f);
        if (l < 32) zbuf[w][l] = z;
        __builtin_amdgcn_wave_barrier();

        f32x16 c0 = {0,0,0,0,0,0,0,0,0,0,0,0,0,0,0,0};
        f32x16 c1 = {0,0,0,0,0,0,0,0,0,0,0,0,0,0,0,0};
        #pragma unroll
        for (int st = 0; st < 4; ++st) {
            c0 = __builtin_amdgcn_mfma_f32_32x32x16_bf16(af[st], bfr[st][0], c0, 0, 0, 0);
            c1 = __builtin_amdgcn_mfma_f32_32x32x16_bf16(af[st], bfr[st][1], c1, 0, 0, 0);
        }

        float* op = out + base + (size_t)l0 * STRIDE_ + lm;
        #pragma unroll
        for (int r = 0; r < 16; ++r) {
            const int ro = (r & 3) + 8 * (r >> 2) + 4 * lh;
            const float zz = zbuf[w][ro];
            op[(size_t)ro * STRIDE_]      = c0[r] * zz;
            op[(size_t)ro * STRIDE_ + 32] = c1[r] * zz;
        }
        __builtin_amdgcn_wave_barrier();   // zbuf reused next band
    }
}

// ws layout (floats): pkv[NH*SPLIT][4096] | pks[NH*SPLIT][64] |
//                     kvt bf16 (float-sized area) | ksum[NH][64]
extern "C" void kernel_launch(void* const* d_in, const int* in_sizes, int n_in,
                              void* d_out, int out_size, void* d_ws, size_t ws_size,
                              hipStream_t stream) {
    (void)in_sizes; (void)n_in; (void)out_size; (void)ws_size;
    const float* qq = (const float*)d_in[0];
    const float* kk = (const float*)d_in[1];
    const float* vv = (const float*)d_in[2];
    float* outp = (float*)d_out;
    float* ws   = (float*)d_ws;

    constexpr int SPLIT = 16;      // 8.6 MB partials -- always fits
    float* pkv = ws;
    float* pks = ws + (size_t)NH_ * SPLIT * (E_ * E_);
    unsigned short* kvt = (unsigned short*)(pks + (size_t)NH_ * SPLIT * E_);
    float* ksm = (float*)(kvt + (size_t)NH_ * (E_ * E_));

    la_kv<SPLIT><<<NH_ * SPLIT, 256, 0, stream>>>(kk, vv, pkv, pks);
    la_reduce<SPLIT><<<NH_ * 16, 256, 0, stream>>>(pkv, pks, kvt, ksm);
    la_out<<<NH_ * 32, 256, 0, stream>>>(qq, kvt, ksm, outp);
}